// Round 6
// baseline (372.707 us; speedup 1.0000x reference)
//
#include <hip/hip_runtime.h>

#define ZD 21
#define YD 256
#define XD 256
#define BD 2
#define NCIN 16
#define NC1 32
#define NC2 64
#define BN_EPS 1e-3f

typedef __attribute__((ext_vector_type(8))) short short8;
typedef __attribute__((ext_vector_type(4))) float floatx4;

__device__ inline void rne_split(float w, short& h, short& l) {
    unsigned b = __float_as_uint(w);
    unsigned hb = (b + 0x7FFFu + ((b >> 16) & 1u)) >> 16;
    float hf = __uint_as_float(hb << 16);
    float lf = w - hf;
    unsigned lb2 = __float_as_uint(lf);
    unsigned lb = (lb2 + 0x7FFFu + ((lb2 >> 16) & 1u)) >> 16;
    h = (short)hb; l = (short)lb;
}

__device__ inline void trunc_split(float v, short& h, short& l) {
    unsigned b = __float_as_uint(v);
    unsigned hb = b >> 16;
    float hf = __uint_as_float(hb << 16);
    float lf = v - hf;
    h = (short)hb;
    l = (short)(__float_as_uint(lf) >> 16);
}

// conv1 lookup: offset ko in [0,27), kernel offset -1..1 per dim
__device__ inline int lookup1(const int* __restrict__ grid, bool rok,
                              int bb, int z0, int y0, int x0, int ko) {
    if (!rok || ko >= 27) return -1;
    const int z = z0 + ko / 9 - 1;
    const int y = y0 + (ko / 3) % 3 - 1;
    const int x = x0 + ko % 3 - 1;
    if ((unsigned)z >= ZD || (unsigned)y >= YD || (unsigned)x >= XD) return -1;
    return grid[((bb * ZD + z) * YD + y) * XD + x];
}

// conv2 lookup: z0/y0/x0 already hold o*2 - pad
__device__ inline int lookup2(const int* __restrict__ grid, bool rok,
                              int bb, int z0, int y0, int x0, int k) {
    if (!rok) return -1;
    const int z = z0 + k / 9;
    const int y = y0 + (k / 3) % 3;
    const int x = x0 + k % 3;
    if ((unsigned)z >= ZD || (unsigned)y >= YD || (unsigned)x >= XD) return -1;
    return grid[((bb * ZD + z) * YD + y) * XD + x];
}

__global__ __launch_bounds__(256) void scatter_grid_k(const int* __restrict__ coors,
                                                      int* __restrict__ grid, int n) {
    int i = blockIdx.x * 256 + threadIdx.x;
    if (i >= n) return;
    const int4 c = ((const int4*)coors)[i];   // [b, z, y, x]
    const int lin = ((c.x * ZD + c.y) * YD + c.z) * XD + c.w;
    grid[lin] = i;
}

// Pack W1 (pairs of offsets stacked to K=32) and W2 into MFMA B-fragment
// layout, hi/lo bf16 split. B-frag for 16x16x32: lane holds B[k=quad*8+j][n=lane&15].
__global__ __launch_bounds__(256) void pack_w_k(const float* __restrict__ W1,
                                                const float* __restrict__ W2,
                                                short* __restrict__ wp1,
                                                short* __restrict__ wp2) {
    int t = blockIdx.x * 256 + threadIdx.x;
    if (t < 14 * 2 * 512) {               // Wp1: [pair][cb][term][512]
        int pair = t / 1024, r = t % 1024, cb = r / 512, e = r % 512;
        int lane = e / 8, j = e % 8, quad = lane >> 4, kk = quad * 8 + j;
        int ko = pair * 2 + (kk >> 4), ci = kk & 15, co = cb * 16 + (lane & 15);
        float w = (ko < 27) ? W1[(ko * NCIN + ci) * NC1 + co] : 0.f;
        short h, l; rne_split(w, h, l);
        wp1[((pair * 2 + cb) * 2 + 0) * 512 + e] = h;
        wp1[((pair * 2 + cb) * 2 + 1) * 512 + e] = l;
    }
    int t2 = t - 14 * 2 * 512;
    if (t2 >= 0 && t2 < 27 * 4 * 512) {   // Wp2: [k][cb][term][512]
        int k = t2 / 2048, r = t2 % 2048, cb = r / 512, e = r % 512;
        int lane = e / 8, j = e % 8, ci = (lane >> 4) * 8 + j, co = cb * 16 + (lane & 15);
        float w = W2[(k * NC1 + ci) * NC2 + co];
        short h, l; rne_split(w, h, l);
        wp2[((k * 4 + cb) * 2 + 0) * 512 + e] = h;
        wp2[((k * 4 + cb) * 2 + 1) * 512 + e] = l;
    }
}

// wave = 64 consecutive output voxels (4 M-tiles of 16). K=32 = 2 offsets x 16 ci.
// B fragments loaded once per pair, reused across 4 M-tiles. Grid lookups
// software-pipelined one pair ahead.
__global__ __launch_bounds__(256, 3) void conv1_k(
    const float* __restrict__ feat, const int* __restrict__ coors,
    const short* __restrict__ wp1,
    const float* __restrict__ g1, const float* __restrict__ b1,
    const float* __restrict__ m1, const float* __restrict__ v1,
    const int* __restrict__ grid, unsigned short* __restrict__ f1hi,
    unsigned short* __restrict__ f1lo, int n) {
    const int tid = threadIdx.x;
    const int lane = tid & 63;
    const int quad = lane >> 4;
    const int mrow = lane & 15;
    const int vbase = (blockIdx.x * 4 + (tid >> 6)) * 64;

    int bb[4], z0[4], y0[4], x0[4];
    bool rok[4];
#pragma unroll
    for (int mt = 0; mt < 4; ++mt) {
        const int v = vbase + mt * 16 + mrow;
        rok[mt] = v < n;
        bb[mt] = 0; z0[mt] = 0; y0[mt] = 0; x0[mt] = 0;
        if (rok[mt]) {
            const int4 cc = ((const int4*)coors)[v];
            bb[mt] = cc.x; z0[mt] = cc.y; y0[mt] = cc.z; x0[mt] = cc.w;
        }
    }

    floatx4 d[4][2];
#pragma unroll
    for (int mt = 0; mt < 4; ++mt)
#pragma unroll
        for (int cb = 0; cb < 2; ++cb) d[mt][cb] = (floatx4){0.f, 0.f, 0.f, 0.f};

    const short8* __restrict__ wb = (const short8*)wp1;
    const int ko_add = quad >> 1;     // this quad's offset within the pair
    const int ci_half = quad & 1;     // this quad's input-channel half

    int cur[4];
#pragma unroll
    for (int mt = 0; mt < 4; ++mt)
        cur[mt] = lookup1(grid, rok[mt], bb[mt], z0[mt], y0[mt], x0[mt], ko_add);

#pragma unroll 1
    for (int pair = 0; pair < 14; ++pair) {
        int nxt[4];
#pragma unroll
        for (int mt = 0; mt < 4; ++mt)
            nxt[mt] = (pair + 1 < 14)
                ? lookup1(grid, rok[mt], bb[mt], z0[mt], y0[mt], x0[mt],
                          (pair + 1) * 2 + ko_add)
                : -1;

        short8 ahi[4], alo[4];
        unsigned long long bm[4];
#pragma unroll
        for (int mt = 0; mt < 4; ++mt) {
            bm[mt] = __ballot(cur[mt] >= 0);
            ahi[mt] = (short8)0; alo[mt] = (short8)0;
            if (cur[mt] >= 0) {
                const float4* fr = (const float4*)(feat + (size_t)cur[mt] * NCIN + ci_half * 8);
                const float4 a = fr[0], b = fr[1];
                float v[8] = {a.x, a.y, a.z, a.w, b.x, b.y, b.z, b.w};
#pragma unroll
                for (int i = 0; i < 8; ++i) {
                    short h, l; trunc_split(v[i], h, l);
                    ahi[mt][i] = h; alo[mt][i] = l;
                }
            }
        }

        const short8 b0h = wb[((pair * 2 + 0) * 2 + 0) * 64 + lane];
        const short8 b0l = wb[((pair * 2 + 0) * 2 + 1) * 64 + lane];
        const short8 b1h = wb[((pair * 2 + 1) * 2 + 0) * 64 + lane];
        const short8 b1l = wb[((pair * 2 + 1) * 2 + 1) * 64 + lane];
#pragma unroll
        for (int mt = 0; mt < 4; ++mt) {
            if (bm[mt]) {
                d[mt][0] = __builtin_amdgcn_mfma_f32_16x16x32_bf16(ahi[mt], b0h, d[mt][0], 0, 0, 0);
                d[mt][0] = __builtin_amdgcn_mfma_f32_16x16x32_bf16(ahi[mt], b0l, d[mt][0], 0, 0, 0);
                d[mt][0] = __builtin_amdgcn_mfma_f32_16x16x32_bf16(alo[mt], b0h, d[mt][0], 0, 0, 0);
                d[mt][1] = __builtin_amdgcn_mfma_f32_16x16x32_bf16(ahi[mt], b1h, d[mt][1], 0, 0, 0);
                d[mt][1] = __builtin_amdgcn_mfma_f32_16x16x32_bf16(ahi[mt], b1l, d[mt][1], 0, 0, 0);
                d[mt][1] = __builtin_amdgcn_mfma_f32_16x16x32_bf16(alo[mt], b1h, d[mt][1], 0, 0, 0);
            }
        }
#pragma unroll
        for (int mt = 0; mt < 4; ++mt) cur[mt] = nxt[mt];
    }

    // C/D layout: col = lane&15 (channel), row = quad*4 + reg (voxel)
    const int col = lane & 15;
#pragma unroll
    for (int cb = 0; cb < 2; ++cb) {
        const int ch = cb * 16 + col;
        const float sc = g1[ch] * rsqrtf(v1[ch] + BN_EPS);
        const float sb = b1[ch] - m1[ch] * sc;
#pragma unroll
        for (int mt = 0; mt < 4; ++mt) {
#pragma unroll
            for (int r = 0; r < 4; ++r) {
                const int v = vbase + mt * 16 + quad * 4 + r;
                if (v < n) {
                    const float o = fmaxf(fmaf(d[mt][cb][r], sc, sb), 0.f);
                    short h, l; trunc_split(o, h, l);
                    f1hi[(size_t)v * NC1 + ch] = (unsigned short)h;
                    f1lo[(size_t)v * NC1 + ch] = (unsigned short)l;
                }
            }
        }
    }
}

// wave = 64 consecutive output voxels (4 M-tiles), N=64 (4 col-blocks), K=32.
// A held for all 4 M-tiles; B loaded once per (k,cb), reused 4x. Lookups
// pipelined one offset ahead.
__global__ __launch_bounds__(256, 3) void conv2_k(
    const unsigned short* __restrict__ f1hi, const unsigned short* __restrict__ f1lo,
    const int* __restrict__ ocoors, const short* __restrict__ wp2,
    const float* __restrict__ g2, const float* __restrict__ b2,
    const float* __restrict__ m2, const float* __restrict__ v2,
    const int* __restrict__ grid, float* __restrict__ out, int m) {
    const int tid = threadIdx.x;
    const int lane = tid & 63;
    const int quad = lane >> 4;
    const int mrow = lane & 15;
    const int vbase = (blockIdx.x * 4 + (tid >> 6)) * 64;

    int bb[4], z0[4], y0[4], x0[4];
    bool rok[4];
#pragma unroll
    for (int mt = 0; mt < 4; ++mt) {
        const int v = vbase + mt * 16 + mrow;
        rok[mt] = v < m;
        bb[mt] = 0; z0[mt] = 0; y0[mt] = 0; x0[mt] = 0;
        if (rok[mt]) {
            const int4 cc = ((const int4*)ocoors)[v];
            bb[mt] = cc.x; z0[mt] = cc.y * 2; y0[mt] = cc.z * 2 - 1; x0[mt] = cc.w * 2 - 1;
        }
    }

    floatx4 d[4][4];
#pragma unroll
    for (int mt = 0; mt < 4; ++mt)
#pragma unroll
        for (int cb = 0; cb < 4; ++cb) d[mt][cb] = (floatx4){0.f, 0.f, 0.f, 0.f};

    const short8* __restrict__ wb = (const short8*)wp2;

    int cur[4];
#pragma unroll
    for (int mt = 0; mt < 4; ++mt)
        cur[mt] = lookup2(grid, rok[mt], bb[mt], z0[mt], y0[mt], x0[mt], 0);

#pragma unroll 1
    for (int k = 0; k < 27; ++k) {
        int nxt[4];
#pragma unroll
        for (int mt = 0; mt < 4; ++mt)
            nxt[mt] = (k + 1 < 27)
                ? lookup2(grid, rok[mt], bb[mt], z0[mt], y0[mt], x0[mt], k + 1)
                : -1;

        short8 ahi[4], alo[4];
        unsigned long long bm[4];
#pragma unroll
        for (int mt = 0; mt < 4; ++mt) {
            bm[mt] = __ballot(cur[mt] >= 0);
            ahi[mt] = (short8)0; alo[mt] = (short8)0;
            if (cur[mt] >= 0) {
                ahi[mt] = *(const short8*)(f1hi + (size_t)cur[mt] * NC1 + quad * 8);
                alo[mt] = *(const short8*)(f1lo + (size_t)cur[mt] * NC1 + quad * 8);
            }
        }

#pragma unroll
        for (int cb = 0; cb < 4; ++cb) {
            const short8 bh = wb[((k * 4 + cb) * 2 + 0) * 64 + lane];
            const short8 bl = wb[((k * 4 + cb) * 2 + 1) * 64 + lane];
#pragma unroll
            for (int mt = 0; mt < 4; ++mt) {
                if (bm[mt]) {
                    d[mt][cb] = __builtin_amdgcn_mfma_f32_16x16x32_bf16(ahi[mt], bh, d[mt][cb], 0, 0, 0);
                    d[mt][cb] = __builtin_amdgcn_mfma_f32_16x16x32_bf16(ahi[mt], bl, d[mt][cb], 0, 0, 0);
                    d[mt][cb] = __builtin_amdgcn_mfma_f32_16x16x32_bf16(alo[mt], bh, d[mt][cb], 0, 0, 0);
                }
            }
        }
#pragma unroll
        for (int mt = 0; mt < 4; ++mt) cur[mt] = nxt[mt];
    }

    const int col = lane & 15;
#pragma unroll
    for (int cb = 0; cb < 4; ++cb) {
        const int ch = cb * 16 + col;
        const float sc = g2[ch] * rsqrtf(v2[ch] + BN_EPS);
        const float sb = b2[ch] - m2[ch] * sc;
#pragma unroll
        for (int mt = 0; mt < 4; ++mt) {
#pragma unroll
            for (int r = 0; r < 4; ++r) {
                const int v = vbase + mt * 16 + quad * 4 + r;
                if (v < m)
                    out[(size_t)v * NC2 + ch] = fmaxf(fmaf(d[mt][cb][r], sc, sb), 0.f);
            }
        }
    }
}

// out_coors passthrough (as float values) + batch_size
__global__ __launch_bounds__(256) void tail_k(const int* __restrict__ oc,
                                              const int* __restrict__ bs,
                                              float* __restrict__ out, int m4) {
    int i = blockIdx.x * 256 + threadIdx.x;
    if (i < m4) out[i] = (float)oc[i];
    if (i == m4) out[m4] = (float)bs[0];
}

extern "C" void kernel_launch(void* const* d_in, const int* in_sizes, int n_in,
                              void* d_out, int out_size, void* d_ws, size_t ws_size,
                              hipStream_t stream) {
    const float* feat  = (const float*)d_in[0];
    const int*   coors = (const int*)d_in[1];
    const int*   ocoors= (const int*)d_in[2];
    const float* W1 = (const float*)d_in[3];
    const float* g1 = (const float*)d_in[4];
    const float* b1 = (const float*)d_in[5];
    const float* m1 = (const float*)d_in[6];
    const float* v1 = (const float*)d_in[7];
    const float* W2 = (const float*)d_in[8];
    const float* g2 = (const float*)d_in[9];
    const float* b2 = (const float*)d_in[10];
    const float* m2 = (const float*)d_in[11];
    const float* v2 = (const float*)d_in[12];
    const int*   bs = (const int*)d_in[13];

    const int n = in_sizes[0] / NCIN;
    const int m = in_sizes[2] / 4;

    const size_t GRID_N = (size_t)BD * ZD * YD * XD;
    char* ws = (char*)d_ws;
    int* grid = (int*)ws;
    size_t off = (GRID_N * sizeof(int) + 255) & ~(size_t)255;
    unsigned short* f1hi = (unsigned short*)(ws + off);
    off += ((size_t)n * NC1 * 2 + 255) & ~(size_t)255;
    unsigned short* f1lo = (unsigned short*)(ws + off);
    off += ((size_t)n * NC1 * 2 + 255) & ~(size_t)255;
    short* wp1 = (short*)(ws + off);
    off += (14 * 2 * 2 * 512 * 2 + 255) & ~(size_t)255;
    short* wp2 = (short*)(ws + off);

    hipMemsetAsync(grid, 0xFF, GRID_N * sizeof(int), stream);
    scatter_grid_k<<<(n + 255) / 256, 256, 0, stream>>>(coors, grid, n);
    pack_w_k<<<(14 * 1024 + 27 * 2048 + 255) / 256, 256, 0, stream>>>(W1, W2, wp1, wp2);

    conv1_k<<<(n + 255) / 256, 256, 0, stream>>>(feat, coors, wp1, g1, b1, m1, v1,
                                                 grid, f1hi, f1lo, n);

    float* out = (float*)d_out;
    conv2_k<<<(m + 255) / 256, 256, 0, stream>>>(f1hi, f1lo, ocoors, wp2,
                                                 g2, b2, m2, v2, grid, out, m);
    tail_k<<<(m * 4 + 1 + 255) / 256, 256, 0, stream>>>(ocoors, bs, out + (size_t)m * NC2, m * 4);
}